// Round 6
// baseline (35.380 us; speedup 1.0000x reference)
//
#include <hip/hip_runtime.h>
#include <math.h>

#define SEQ   8
#define DFF   32
#define NL    2
#define VOCAB 256
#define BATCH 131072
#define TBL_N 1024   // intervals; entry i packs f(nd_i), f(nd_{i+1}); 16 KiB/layer -> L1-resident

typedef float f32x4 __attribute__((ext_vector_type(4)));   // clang-native for nontemporal builtin

// Parallel table builder: one 32-lane half-wave per entry; lane j computes the
// j-th GELU term at both interval endpoints, butterfly-reduce, lane 0 writes.
__global__ __launch_bounds__(256) void build_tables_par(
    const float* __restrict__ W1, const float* __restrict__ b1,
    const float* __restrict__ W2, const float* __restrict__ b2,
    const float* __restrict__ g1, const float* __restrict__ be1,
    float4* __restrict__ T4)
{
    int gt    = blockIdx.x * 256 + threadIdx.x;
    int entry = gt >> 5;
    int j     = gt & 31;
    if (entry >= NL * TBL_N) return;
    int l = entry >> 10;            // / TBL_N
    int i = entry & (TBL_N - 1);

    float nd0 = -1.0f + (float)i * (2.0f / TBL_N);
    float nd1 = nd0 + (2.0f / TBL_N);

    float ga = g1[l*2+0], gb = g1[l*2+1], ba = be1[l*2+0], bb = be1[l*2+1];
    float w1a = W1[l*64 + j*2], w1b = W1[l*64 + j*2 + 1], b1j = b1[l*32 + j];
    float w2a = W2[l*64 + j],   w2b = W2[l*64 + 32 + j];

    // endpoint 0
    float h0 = fmaf( nd0, ga, ba), h1 = fmaf(-nd0, gb, bb);
    float t  = fmaf(w1a, h0, fmaf(w1b, h1, b1j));
    float g  = 0.5f * t * (1.0f + erff(t * 0.70710678118654752f));
    float f00 = g * w2a, f10 = g * w2b;
    // endpoint 1
    h0 = fmaf( nd1, ga, ba); h1 = fmaf(-nd1, gb, bb);
    t  = fmaf(w1a, h0, fmaf(w1b, h1, b1j));
    g  = 0.5f * t * (1.0f + erff(t * 0.70710678118654752f));
    float f01 = g * w2a, f11 = g * w2b;

    #pragma unroll
    for (int m = 1; m < 32; m <<= 1) {
        f00 += __shfl_xor(f00, m, 32);
        f10 += __shfl_xor(f10, m, 32);
        f01 += __shfl_xor(f01, m, 32);
        f11 += __shfl_xor(f11, m, 32);
    }
    if (j == 0) {
        T4[entry] = make_float4(f00 + b2[l*2+0], f10 + b2[l*2+1],
                                f01 + b2[l*2+0], f11 + b2[l*2+1]);
    }
}

// 8 lanes per batch element (lane = position); k/v exchanged via __shfl width 8.
// FF via table lookup in nd; final vocab row = nd_final*u + w.
__global__ __launch_bounds__(256, 8) void seqtx_main(
    const int*   __restrict__ x,
    const float* __restrict__ Wqkv, const float* __restrict__ bqkv,
    const float* __restrict__ Wo,   const float* __restrict__ bo,
    const float* __restrict__ g1,   const float* __restrict__ be1,
    const float* __restrict__ g2,   const float* __restrict__ be2,
    const float* __restrict__ Wout, const float* __restrict__ bout,
    const float4* __restrict__ T4,
    float* __restrict__ out)
{
    __shared__ float snd[32];

    const int tid = threadIdx.x;
    const int sub = tid & 7;
    const int gid = blockIdx.x * 256 + tid;

    float h0 = (float)x[gid] * (1.0f / 255.0f);
    float h1 = (float)sub * (1.0f / 7.0f);
    float ndl = 0.0f;

    #pragma unroll
    for (int l = 0; l < NL; ++l) {
        // ---- QKV projection (uniform scalar weights) ----
        const float* wq = Wqkv + l * 12;
        const float* bq = bqkv + l * 6;
        float q0 = fmaf(wq[0],  h0, fmaf(wq[1],  h1, bq[0]));
        float q1 = fmaf(wq[2],  h0, fmaf(wq[3],  h1, bq[1]));
        float k0 = fmaf(wq[4],  h0, fmaf(wq[5],  h1, bq[2]));
        float k1 = fmaf(wq[6],  h0, fmaf(wq[7],  h1, bq[3]));
        float v0 = fmaf(wq[8],  h0, fmaf(wq[9],  h1, bq[4]));
        float v1 = fmaf(wq[10], h0, fmaf(wq[11], h1, bq[5]));

        // ---- attention, hd=1, scale=1; softmax without max-sub (|s| small) ----
        float q0e = q0 * 1.44269504f;    // fold log2(e) into q
        float q1e = q1 * 1.44269504f;
        float s0 = 0.0f, a0 = 0.0f, s1 = 0.0f, a1 = 0.0f;
        #pragma unroll
        for (int j = 0; j < SEQ; ++j) {
            float kj0 = __shfl(k0, j, SEQ);
            float vj0 = __shfl(v0, j, SEQ);
            float e0  = __builtin_amdgcn_exp2f(q0e * kj0);
            s0 += e0;  a0 = fmaf(e0, vj0, a0);
            float kj1 = __shfl(k1, j, SEQ);
            float vj1 = __shfl(v1, j, SEQ);
            float e1  = __builtin_amdgcn_exp2f(q1e * kj1);
            s1 += e1;  a1 = fmaf(e1, vj1, a1);
        }
        float o0 = a0 * __builtin_amdgcn_rcpf(s0);
        float o1 = a1 * __builtin_amdgcn_rcpf(s1);

        // ---- output proj + residual + LN1 (closed form, D=2) ----
        const float* wo = Wo + l * 4;
        float p0 = fmaf(wo[0], o0, fmaf(wo[1], o1, bo[l * 2 + 0]));
        float p1 = fmaf(wo[2], o0, fmaf(wo[3], o1, bo[l * 2 + 1]));
        float a = h0 + p0, c = h1 + p1;
        float d = 0.5f * (a - c);
        float nd = d * __builtin_amdgcn_rsqf(fmaf(d, d, 1e-5f));
        h0 = fmaf( nd, g1[l * 2 + 0], be1[l * 2 + 0]);
        h1 = fmaf(-nd, g1[l * 2 + 1], be1[l * 2 + 1]);

        // ---- FF via table lookup + lerp ----
        float tf = fmaf(nd, (float)(TBL_N / 2), (float)(TBL_N / 2)); // (nd+1)*N/2
        int   i  = (int)tf;
        i = (i < 0) ? 0 : ((i > TBL_N - 1) ? TBL_N - 1 : i);
        float fr = tf - (float)i;
        float4 e4 = T4[l * TBL_N + i];       // (f0_i, f1_i, f0_i1, f1_i1)
        float f0 = fmaf(fr, e4.z - e4.x, e4.x);
        float f1 = fmaf(fr, e4.w - e4.y, e4.y);

        // ---- residual + LN2 (exact) ----
        a = h0 + f0;  c = h1 + f1;
        d = 0.5f * (a - c);
        float nd2 = d * __builtin_amdgcn_rsqf(fmaf(d, d, 1e-5f));
        h0 = fmaf( nd2, g2[l * 2 + 0], be2[l * 2 + 0]);
        h1 = fmaf(-nd2, g2[l * 2 + 1], be2[l * 2 + 1]);
        ndl = nd2;
    }

    if (sub == SEQ - 1) snd[tid >> 3] = ndl;
    __syncthreads();

    // ---- vocab projection: out[row][v] = nd_final*u[v] + w[v] ----
    // Per store instruction the wave covers one full 1 KiB row (64 lanes x 16B).
    // Nontemporal: the 128 MiB output stream is never re-read — don't allocate L2.
    const int r  = tid >> 6;              // wave id -> row offset (uniform/wave)
    const int cg = (tid & 63) * 4;

    const float2* wvp = reinterpret_cast<const float2*>(Wout);
    float2 wv0 = wvp[cg + 0];
    float2 wv1 = wvp[cg + 1];
    float2 wv2 = wvp[cg + 2];
    float2 wv3 = wvp[cg + 3];
    float4 bv  = *reinterpret_cast<const float4*>(bout + cg);
    float gf0 = g2[2], gf1 = g2[3], bf0 = be2[2], bf1 = be2[3];

    float u0 = wv0.x * gf0 - wv0.y * gf1,  w0 = fmaf(wv0.x, bf0, fmaf(wv0.y, bf1, bv.x));
    float u1 = wv1.x * gf0 - wv1.y * gf1,  w1 = fmaf(wv1.x, bf0, fmaf(wv1.y, bf1, bv.y));
    float u2 = wv2.x * gf0 - wv2.y * gf1,  w2 = fmaf(wv2.x, bf0, fmaf(wv2.y, bf1, bv.z));
    float u3 = wv3.x * gf0 - wv3.y * gf1,  w3 = fmaf(wv3.x, bf0, fmaf(wv3.y, bf1, bv.w));

    const size_t rowbase = (size_t)blockIdx.x * 32;
    #pragma unroll
    for (int it = 0; it < 8; ++it) {
        int row = it * 4 + r;
        float ndv = snd[row];             // LDS broadcast (wave-uniform row)
        f32x4 res;
        res.x = fmaf(ndv, u0, w0);
        res.y = fmaf(ndv, u1, w1);
        res.z = fmaf(ndv, u2, w2);
        res.w = fmaf(ndv, u3, w3);
        __builtin_nontemporal_store(res,
            reinterpret_cast<f32x4*>(&out[(rowbase + row) * VOCAB + cg]));
    }
}

extern "C" void kernel_launch(void* const* d_in, const int* in_sizes, int n_in,
                              void* d_out, int out_size, void* d_ws, size_t ws_size,
                              hipStream_t stream) {
    const int*   x    = (const int*)  d_in[0];
    const float* Wqkv = (const float*)d_in[1];
    const float* bqkv = (const float*)d_in[2];
    const float* Wo   = (const float*)d_in[3];
    const float* bo   = (const float*)d_in[4];
    const float* W1   = (const float*)d_in[5];
    const float* b1   = (const float*)d_in[6];
    const float* W2   = (const float*)d_in[7];
    const float* b2   = (const float*)d_in[8];
    const float* g1   = (const float*)d_in[9];
    const float* be1  = (const float*)d_in[10];
    const float* g2   = (const float*)d_in[11];
    const float* be2  = (const float*)d_in[12];
    const float* Wout = (const float*)d_in[13];
    const float* bout = (const float*)d_in[14];
    float* out = (float*)d_out;

    float4* T4 = (float4*)d_ws;   // 2*1024*16B = 32 KiB

    // NL*TBL_N entries, 32 threads each -> 65536 threads -> 256 blocks
    build_tables_par<<<(NL * TBL_N * 32) / 256, 256, 0, stream>>>(
        W1, b1, W2, b2, g1, be1, T4);

    seqtx_main<<<BATCH / 32, 256, 0, stream>>>(
        x, Wqkv, bqkv, Wo, bo, g1, be1, g2, be2, Wout, bout, T4, out);
}

// Round 7
// 33.865 us; speedup vs baseline: 1.0447x; 1.0447x over previous
//
#include <hip/hip_runtime.h>
#include <math.h>

#define SEQ   8
#define DFF   32
#define NL    2
#define VOCAB 256
#define BATCH 131072
#define TBL_N 1024   // intervals; entry i packs f(nd_i), f(nd_{i+1})

// Parallel table builder: one 32-lane half-wave per entry; lane j computes the
// j-th GELU term at both interval endpoints, butterfly-reduce, lane 0 writes.
__global__ __launch_bounds__(256) void build_tables_par(
    const float* __restrict__ W1, const float* __restrict__ b1,
    const float* __restrict__ W2, const float* __restrict__ b2,
    const float* __restrict__ g1, const float* __restrict__ be1,
    float4* __restrict__ T4)
{
    int gt    = blockIdx.x * 256 + threadIdx.x;
    int entry = gt >> 5;
    int j     = gt & 31;
    if (entry >= NL * TBL_N) return;
    int l = entry >> 10;            // / TBL_N
    int i = entry & (TBL_N - 1);

    float nd0 = -1.0f + (float)i * (2.0f / TBL_N);
    float nd1 = nd0 + (2.0f / TBL_N);

    float ga = g1[l*2+0], gb = g1[l*2+1], ba = be1[l*2+0], bb = be1[l*2+1];
    float w1a = W1[l*64 + j*2], w1b = W1[l*64 + j*2 + 1], b1j = b1[l*32 + j];
    float w2a = W2[l*64 + j],   w2b = W2[l*64 + 32 + j];

    // endpoint 0
    float h0 = fmaf( nd0, ga, ba), h1 = fmaf(-nd0, gb, bb);
    float t  = fmaf(w1a, h0, fmaf(w1b, h1, b1j));
    float g  = 0.5f * t * (1.0f + erff(t * 0.70710678118654752f));
    float f00 = g * w2a, f10 = g * w2b;
    // endpoint 1
    h0 = fmaf( nd1, ga, ba); h1 = fmaf(-nd1, gb, bb);
    t  = fmaf(w1a, h0, fmaf(w1b, h1, b1j));
    g  = 0.5f * t * (1.0f + erff(t * 0.70710678118654752f));
    float f01 = g * w2a, f11 = g * w2b;

    #pragma unroll
    for (int m = 1; m < 32; m <<= 1) {
        f00 += __shfl_xor(f00, m, 32);
        f10 += __shfl_xor(f10, m, 32);
        f01 += __shfl_xor(f01, m, 32);
        f11 += __shfl_xor(f11, m, 32);
    }
    if (j == 0) {
        T4[entry] = make_float4(f00 + b2[l*2+0], f10 + b2[l*2+1],
                                f01 + b2[l*2+0], f11 + b2[l*2+1]);
    }
}

// 8 lanes per batch element (lane = position). One wave = 8 elements = 8 output
// rows of 1 KiB. No __syncthreads, no LDS: after phase 1 the wave broadcasts
// each element's final nd via __shfl and immediately streams its 8 rows —
// per-wave pipelining so store issue ramps as soon as any wave finishes compute.
__global__ __launch_bounds__(256, 8) void seqtx_main(
    const int*   __restrict__ x,
    const float* __restrict__ Wqkv, const float* __restrict__ bqkv,
    const float* __restrict__ Wo,   const float* __restrict__ bo,
    const float* __restrict__ g1,   const float* __restrict__ be1,
    const float* __restrict__ g2,   const float* __restrict__ be2,
    const float* __restrict__ Wout, const float* __restrict__ bout,
    const float4* __restrict__ T4,
    float* __restrict__ out)
{
    const int tid  = threadIdx.x;
    const int sub  = tid & 7;                      // position within element
    const int gid  = blockIdx.x * 256 + tid;
    const int lane = tid & 63;

    float h0 = (float)x[gid] * (1.0f / 255.0f);
    float h1 = (float)sub * (1.0f / 7.0f);
    float ndl = 0.0f;

    #pragma unroll
    for (int l = 0; l < NL; ++l) {
        // ---- QKV projection (uniform scalar weights) ----
        const float* wq = Wqkv + l * 12;
        const float* bq = bqkv + l * 6;
        float q0 = fmaf(wq[0],  h0, fmaf(wq[1],  h1, bq[0]));
        float q1 = fmaf(wq[2],  h0, fmaf(wq[3],  h1, bq[1]));
        float k0 = fmaf(wq[4],  h0, fmaf(wq[5],  h1, bq[2]));
        float k1 = fmaf(wq[6],  h0, fmaf(wq[7],  h1, bq[3]));
        float v0 = fmaf(wq[8],  h0, fmaf(wq[9],  h1, bq[4]));
        float v1 = fmaf(wq[10], h0, fmaf(wq[11], h1, bq[5]));

        // ---- attention, hd=1, scale=1; softmax without max-sub (|s| small) ----
        float q0e = q0 * 1.44269504f;    // fold log2(e) into q
        float q1e = q1 * 1.44269504f;
        float s0 = 0.0f, a0 = 0.0f, s1 = 0.0f, a1 = 0.0f;
        #pragma unroll
        for (int j = 0; j < SEQ; ++j) {
            float kj0 = __shfl(k0, j, SEQ);
            float vj0 = __shfl(v0, j, SEQ);
            float e0  = __builtin_amdgcn_exp2f(q0e * kj0);
            s0 += e0;  a0 = fmaf(e0, vj0, a0);
            float kj1 = __shfl(k1, j, SEQ);
            float vj1 = __shfl(v1, j, SEQ);
            float e1  = __builtin_amdgcn_exp2f(q1e * kj1);
            s1 += e1;  a1 = fmaf(e1, vj1, a1);
        }
        float o0 = a0 * __builtin_amdgcn_rcpf(s0);
        float o1 = a1 * __builtin_amdgcn_rcpf(s1);

        // ---- output proj + residual + LN1 (closed form, D=2) ----
        const float* wo = Wo + l * 4;
        float p0 = fmaf(wo[0], o0, fmaf(wo[1], o1, bo[l * 2 + 0]));
        float p1 = fmaf(wo[2], o0, fmaf(wo[3], o1, bo[l * 2 + 1]));
        float a = h0 + p0, c = h1 + p1;
        float d = 0.5f * (a - c);
        float nd = d * __builtin_amdgcn_rsqf(fmaf(d, d, 1e-5f));
        h0 = fmaf( nd, g1[l * 2 + 0], be1[l * 2 + 0]);
        h1 = fmaf(-nd, g1[l * 2 + 1], be1[l * 2 + 1]);

        // ---- FF via table lookup + lerp ----
        float tf = fmaf(nd, (float)(TBL_N / 2), (float)(TBL_N / 2)); // (nd+1)*N/2
        int   i  = (int)tf;
        i = (i < 0) ? 0 : ((i > TBL_N - 1) ? TBL_N - 1 : i);
        float fr = tf - (float)i;
        float4 e4 = T4[l * TBL_N + i];       // (f0_i, f1_i, f0_i1, f1_i1)
        float f0 = fmaf(fr, e4.z - e4.x, e4.x);
        float f1 = fmaf(fr, e4.w - e4.y, e4.y);

        // ---- residual + LN2 (exact) ----
        a = h0 + f0;  c = h1 + f1;
        d = 0.5f * (a - c);
        float nd2 = d * __builtin_amdgcn_rsqf(fmaf(d, d, 1e-5f));
        h0 = fmaf( nd2, g2[l * 2 + 0], be2[l * 2 + 0]);
        h1 = fmaf(-nd2, g2[l * 2 + 1], be2[l * 2 + 1]);
        ndl = nd2;
    }

    // ---- vocab projection: out[row][v] = nd_row*u[v] + w[v] ----
    // This wave's 64 lanes cover 8 elements (rows) x 256 vocab; lane handles
    // vocab quad cg..cg+3 for all 8 rows. One 1 KiB dwordx4-store per row.
    const int cg = lane * 4;

    const float2* wvp = reinterpret_cast<const float2*>(Wout);
    float2 wv0 = wvp[cg + 0];
    float2 wv1 = wvp[cg + 1];
    float2 wv2 = wvp[cg + 2];
    float2 wv3 = wvp[cg + 3];
    float4 bv  = *reinterpret_cast<const float4*>(bout + cg);
    float gf0 = g2[2], gf1 = g2[3], bf0 = be2[2], bf1 = be2[3];

    float u0 = wv0.x * gf0 - wv0.y * gf1,  w0 = fmaf(wv0.x, bf0, fmaf(wv0.y, bf1, bv.x));
    float u1 = wv1.x * gf0 - wv1.y * gf1,  w1 = fmaf(wv1.x, bf0, fmaf(wv1.y, bf1, bv.y));
    float u2 = wv2.x * gf0 - wv2.y * gf1,  w2 = fmaf(wv2.x, bf0, fmaf(wv2.y, bf1, bv.z));
    float u3 = wv3.x * gf0 - wv3.y * gf1,  w3 = fmaf(wv3.x, bf0, fmaf(wv3.y, bf1, bv.w));

    const size_t rowbase = (size_t)(gid >> 6) * 8;   // global wave id * 8 rows
    #pragma unroll
    for (int e = 0; e < 8; ++e) {
        float ndv = __shfl(ndl, e * 8 + 7, 64);      // element e's final-pos nd
        float4 res;
        res.x = fmaf(ndv, u0, w0);
        res.y = fmaf(ndv, u1, w1);
        res.z = fmaf(ndv, u2, w2);
        res.w = fmaf(ndv, u3, w3);
        *reinterpret_cast<float4*>(&out[(rowbase + e) * VOCAB + cg]) = res;
    }
}

extern "C" void kernel_launch(void* const* d_in, const int* in_sizes, int n_in,
                              void* d_out, int out_size, void* d_ws, size_t ws_size,
                              hipStream_t stream) {
    const int*   x    = (const int*)  d_in[0];
    const float* Wqkv = (const float*)d_in[1];
    const float* bqkv = (const float*)d_in[2];
    const float* Wo   = (const float*)d_in[3];
    const float* bo   = (const float*)d_in[4];
    const float* W1   = (const float*)d_in[5];
    const float* b1   = (const float*)d_in[6];
    const float* W2   = (const float*)d_in[7];
    const float* b2   = (const float*)d_in[8];
    const float* g1   = (const float*)d_in[9];
    const float* be1  = (const float*)d_in[10];
    const float* g2   = (const float*)d_in[11];
    const float* be2  = (const float*)d_in[12];
    const float* Wout = (const float*)d_in[13];
    const float* bout = (const float*)d_in[14];
    float* out = (float*)d_out;

    float4* T4 = (float4*)d_ws;   // 2*1024*16B = 32 KiB

    // NL*TBL_N entries, 32 threads each -> 65536 threads -> 256 blocks
    build_tables_par<<<(NL * TBL_N * 32) / 256, 256, 0, stream>>>(
        W1, b1, W2, b2, g1, be1, T4);

    seqtx_main<<<BATCH / 32, 256, 0, stream>>>(
        x, Wqkv, bqkv, Wo, bo, g1, be1, g2, be2, Wout, bout, T4, out);
}

// Round 8
// 33.495 us; speedup vs baseline: 1.0563x; 1.0110x over previous
//
#include <hip/hip_runtime.h>
#include <math.h>

#define SEQ   8
#define DFF   32
#define NL    2
#define VOCAB 256
#define BATCH 131072
#define TBL_N 512    // intervals/layer; 8 KiB/layer packed as float4 pairs -> 16 KiB LDS total

// Parallel table builder: one 32-lane half-wave per entry; lane j computes the
// j-th GELU term at both interval endpoints, butterfly-reduce, lane 0 writes.
__global__ __launch_bounds__(256) void build_tables_par(
    const float* __restrict__ W1, const float* __restrict__ b1,
    const float* __restrict__ W2, const float* __restrict__ b2,
    const float* __restrict__ g1, const float* __restrict__ be1,
    float4* __restrict__ T4)
{
    int gt    = blockIdx.x * 256 + threadIdx.x;
    int entry = gt >> 5;
    int j     = gt & 31;
    if (entry >= NL * TBL_N) return;
    int l = entry >> 9;             // / TBL_N
    int i = entry & (TBL_N - 1);

    float nd0 = -1.0f + (float)i * (2.0f / TBL_N);
    float nd1 = nd0 + (2.0f / TBL_N);

    float ga = g1[l*2+0], gb = g1[l*2+1], ba = be1[l*2+0], bb = be1[l*2+1];
    float w1a = W1[l*64 + j*2], w1b = W1[l*64 + j*2 + 1], b1j = b1[l*32 + j];
    float w2a = W2[l*64 + j],   w2b = W2[l*64 + 32 + j];

    // endpoint 0
    float h0 = fmaf( nd0, ga, ba), h1 = fmaf(-nd0, gb, bb);
    float t  = fmaf(w1a, h0, fmaf(w1b, h1, b1j));
    float g  = 0.5f * t * (1.0f + erff(t * 0.70710678118654752f));
    float f00 = g * w2a, f10 = g * w2b;
    // endpoint 1
    h0 = fmaf( nd1, ga, ba); h1 = fmaf(-nd1, gb, bb);
    t  = fmaf(w1a, h0, fmaf(w1b, h1, b1j));
    g  = 0.5f * t * (1.0f + erff(t * 0.70710678118654752f));
    float f01 = g * w2a, f11 = g * w2b;

    #pragma unroll
    for (int m = 1; m < 32; m <<= 1) {
        f00 += __shfl_xor(f00, m, 32);
        f10 += __shfl_xor(f10, m, 32);
        f01 += __shfl_xor(f01, m, 32);
        f11 += __shfl_xor(f11, m, 32);
    }
    if (j == 0) {
        T4[entry] = make_float4(f00 + b2[l*2+0], f10 + b2[l*2+1],
                                f01 + b2[l*2+0], f11 + b2[l*2+1]);
    }
}

// 8 lanes per batch element (lane = position). Table staged in LDS so the
// vector-memory path is write-only during the streaming epilogue. Layer 1
// computes only query position 7 (the only one consumed downstream).
__global__ __launch_bounds__(256, 8) void seqtx_main(
    const int*   __restrict__ x,
    const float* __restrict__ Wqkv, const float* __restrict__ bqkv,
    const float* __restrict__ Wo,   const float* __restrict__ bo,
    const float* __restrict__ g1,   const float* __restrict__ be1,
    const float* __restrict__ g2,   const float* __restrict__ be2,
    const float* __restrict__ Wout, const float* __restrict__ bout,
    const float4* __restrict__ T4,
    float* __restrict__ out)
{
    __shared__ float4 tbl[NL * TBL_N];          // 16 KiB

    const int tid  = threadIdx.x;
    const int sub  = tid & 7;
    const int gid  = blockIdx.x * 256 + tid;
    const int lane = tid & 63;

    // stage table: 1024 float4, 4 coalesced 16B loads/thread
    #pragma unroll
    for (int k = 0; k < 4; ++k) tbl[tid + k * 256] = T4[tid + k * 256];

    // issue epilogue weight loads early (latency hidden under phase 1)
    const int cg = lane * 4;
    const float2* wvp = reinterpret_cast<const float2*>(Wout);
    float2 wv0 = wvp[cg + 0];
    float2 wv1 = wvp[cg + 1];
    float2 wv2 = wvp[cg + 2];
    float2 wv3 = wvp[cg + 3];
    float4 bv  = *reinterpret_cast<const float4*>(bout + cg);

    float h0 = (float)x[gid] * (1.0f / 255.0f);
    float h1 = (float)sub * (1.0f / 7.0f);

    __syncthreads();                            // table visible

    float ndl;

    // ================= layer 0 (all positions needed) =================
    {
        const float* wq = Wqkv;
        const float* bq = bqkv;
        float q0 = fmaf(wq[0],  h0, fmaf(wq[1],  h1, bq[0]));
        float q1 = fmaf(wq[2],  h0, fmaf(wq[3],  h1, bq[1]));
        float k0 = fmaf(wq[4],  h0, fmaf(wq[5],  h1, bq[2]));
        float k1 = fmaf(wq[6],  h0, fmaf(wq[7],  h1, bq[3]));
        float v0 = fmaf(wq[8],  h0, fmaf(wq[9],  h1, bq[4]));
        float v1 = fmaf(wq[10], h0, fmaf(wq[11], h1, bq[5]));

        float q0e = q0 * 1.44269504f;
        float q1e = q1 * 1.44269504f;
        float s0 = 0.0f, a0 = 0.0f, s1 = 0.0f, a1 = 0.0f;
        #pragma unroll
        for (int j = 0; j < SEQ; ++j) {
            float kj0 = __shfl(k0, j, SEQ);
            float vj0 = __shfl(v0, j, SEQ);
            float e0  = __builtin_amdgcn_exp2f(q0e * kj0);
            s0 += e0;  a0 = fmaf(e0, vj0, a0);
            float kj1 = __shfl(k1, j, SEQ);
            float vj1 = __shfl(v1, j, SEQ);
            float e1  = __builtin_amdgcn_exp2f(q1e * kj1);
            s1 += e1;  a1 = fmaf(e1, vj1, a1);
        }
        float o0 = a0 * __builtin_amdgcn_rcpf(s0);
        float o1 = a1 * __builtin_amdgcn_rcpf(s1);

        float p0 = fmaf(Wo[0], o0, fmaf(Wo[1], o1, bo[0]));
        float p1 = fmaf(Wo[2], o0, fmaf(Wo[3], o1, bo[1]));
        float a = h0 + p0, c = h1 + p1;
        float d = 0.5f * (a - c);
        float nd = d * __builtin_amdgcn_rsqf(fmaf(d, d, 1e-5f));
        h0 = fmaf( nd, g1[0], be1[0]);
        h1 = fmaf(-nd, g1[1], be1[1]);

        float tf = fmaf(nd, (float)(TBL_N / 2), (float)(TBL_N / 2));
        int   i  = (int)tf;
        i = (i < 0) ? 0 : ((i > TBL_N - 1) ? TBL_N - 1 : i);
        float fr = tf - (float)i;
        float4 e4 = tbl[i];
        float f0 = fmaf(fr, e4.z - e4.x, e4.x);
        float f1 = fmaf(fr, e4.w - e4.y, e4.y);

        a = h0 + f0;  c = h1 + f1;
        d = 0.5f * (a - c);
        float nd2 = d * __builtin_amdgcn_rsqf(fmaf(d, d, 1e-5f));
        h0 = fmaf( nd2, g2[0], be2[0]);
        h1 = fmaf(-nd2, g2[1], be2[1]);
    }

    // ================= layer 1 (only query position 7 consumed) =================
    {
        const float* wq = Wqkv + 12;
        const float* bq = bqkv + 6;
        float q0 = fmaf(wq[0],  h0, fmaf(wq[1],  h1, bq[0]));
        float q1 = fmaf(wq[2],  h0, fmaf(wq[3],  h1, bq[1]));
        float k0 = fmaf(wq[4],  h0, fmaf(wq[5],  h1, bq[2]));
        float k1 = fmaf(wq[6],  h0, fmaf(wq[7],  h1, bq[3]));
        float v0 = fmaf(wq[8],  h0, fmaf(wq[9],  h1, bq[4]));
        float v1 = fmaf(wq[10], h0, fmaf(wq[11], h1, bq[5]));

        // q at position 7, folded with log2(e)
        float q0e = __shfl(q0, 7, SEQ) * 1.44269504f;
        float q1e = __shfl(q1, 7, SEQ) * 1.44269504f;
        // each lane contributes its own key/value term
        float e0 = __builtin_amdgcn_exp2f(q0e * k0);
        float e1 = __builtin_amdgcn_exp2f(q1e * k1);
        float n0 = e0 * v0, n1 = e1 * v1;
        #pragma unroll
        for (int m = 1; m < SEQ; m <<= 1) {
            e0 += __shfl_xor(e0, m, SEQ);
            n0 += __shfl_xor(n0, m, SEQ);
            e1 += __shfl_xor(e1, m, SEQ);
            n1 += __shfl_xor(n1, m, SEQ);
        }
        float o0 = n0 * __builtin_amdgcn_rcpf(e0);   // same across the 8-lane group
        float o1 = n1 * __builtin_amdgcn_rcpf(e1);

        float p0 = fmaf(Wo[4], o0, fmaf(Wo[5], o1, bo[2]));
        float p1 = fmaf(Wo[6], o0, fmaf(Wo[7], o1, bo[3]));
        float a = h0 + p0, c = h1 + p1;              // only sub==7 meaningful
        float d = 0.5f * (a - c);
        float nd = d * __builtin_amdgcn_rsqf(fmaf(d, d, 1e-5f));
        float hh0 = fmaf( nd, g1[2], be1[2]);
        float hh1 = fmaf(-nd, g1[3], be1[3]);

        float tf = fmaf(nd, (float)(TBL_N / 2), (float)(TBL_N / 2));
        int   i  = (int)tf;
        i = (i < 0) ? 0 : ((i > TBL_N - 1) ? TBL_N - 1 : i);
        float fr = tf - (float)i;
        float4 e4 = tbl[TBL_N + i];
        float f0 = fmaf(fr, e4.z - e4.x, e4.x);
        float f1 = fmaf(fr, e4.w - e4.y, e4.y);

        a = hh0 + f0;  c = hh1 + f1;
        d = 0.5f * (a - c);
        ndl = d * __builtin_amdgcn_rsqf(fmaf(d, d, 1e-5f));
    }

    // ---- vocab projection: out[row][v] = nd_row*u[v] + w[v] ----
    // Wave covers 8 elements x 256 vocab; one 1 KiB dwordx4-store per row.
    float gf0 = g2[2], gf1 = g2[3], bf0 = be2[2], bf1 = be2[3];
    float u0 = wv0.x * gf0 - wv0.y * gf1,  w0 = fmaf(wv0.x, bf0, fmaf(wv0.y, bf1, bv.x));
    float u1 = wv1.x * gf0 - wv1.y * gf1,  w1 = fmaf(wv1.x, bf0, fmaf(wv1.y, bf1, bv.y));
    float u2 = wv2.x * gf0 - wv2.y * gf1,  w2 = fmaf(wv2.x, bf0, fmaf(wv2.y, bf1, bv.z));
    float u3 = wv3.x * gf0 - wv3.y * gf1,  w3 = fmaf(wv3.x, bf0, fmaf(wv3.y, bf1, bv.w));

    const size_t rowbase = (size_t)(gid >> 6) * 8;   // global wave id * 8 rows
    #pragma unroll
    for (int e = 0; e < 8; ++e) {
        float ndv = __shfl(ndl, e * 8 + 7, 64);      // element e's final nd (from its sub-7 lane)
        float4 res;
        res.x = fmaf(ndv, u0, w0);
        res.y = fmaf(ndv, u1, w1);
        res.z = fmaf(ndv, u2, w2);
        res.w = fmaf(ndv, u3, w3);
        *reinterpret_cast<float4*>(&out[(rowbase + e) * VOCAB + cg]) = res;
    }
}

extern "C" void kernel_launch(void* const* d_in, const int* in_sizes, int n_in,
                              void* d_out, int out_size, void* d_ws, size_t ws_size,
                              hipStream_t stream) {
    const int*   x    = (const int*)  d_in[0];
    const float* Wqkv = (const float*)d_in[1];
    const float* bqkv = (const float*)d_in[2];
    const float* Wo   = (const float*)d_in[3];
    const float* bo   = (const float*)d_in[4];
    const float* W1   = (const float*)d_in[5];
    const float* b1   = (const float*)d_in[6];
    const float* W2   = (const float*)d_in[7];
    const float* b2   = (const float*)d_in[8];
    const float* g1   = (const float*)d_in[9];
    const float* be1  = (const float*)d_in[10];
    const float* g2   = (const float*)d_in[11];
    const float* be2  = (const float*)d_in[12];
    const float* Wout = (const float*)d_in[13];
    const float* bout = (const float*)d_in[14];
    float* out = (float*)d_out;

    float4* T4 = (float4*)d_ws;   // NL*TBL_N*16B = 16 KiB

    // NL*TBL_N entries, 32 threads each -> 32768 threads -> 128 blocks
    build_tables_par<<<(NL * TBL_N * 32) / 256, 256, 0, stream>>>(
        W1, b1, W2, b2, g1, be1, T4);

    seqtx_main<<<BATCH / 32, 256, 0, stream>>>(
        x, Wqkv, bqkv, Wo, bo, g1, be1, g2, be2, Wout, bout, T4, out);
}